// Round 1
// baseline (123.497 us; speedup 1.0000x reference)
//
#include <hip/hip_runtime.h>
#include <hip/hip_bf16.h>

#define BB 4      // batch
#define SS 1023   // source length = 2T-1
#define TT 512    // window length
#define CC 1024   // embed dim
#define DD 64     // head size
#define NROW (BB*SS)    // 4092
#define NROWP 4096      // padded kT row stride: kT[d][b*1024 + s]

typedef float f4 __attribute__((ext_vector_type(4)));
typedef float f2 __attribute__((ext_vector_type(2)));
typedef short bf16x8 __attribute__((ext_vector_type(8)));
typedef float f32x4 __attribute__((ext_vector_type(4)));

// RTN bf16 split: v ~= hi + lo (packed u32 lo<<16|hi).
// SESSION INVARIANT: this split + ALL FOUR MFMA products is the only
// verified-passing config (r12/r13: 0.0156). Manual trunc/half-up splits
// with al*bl dropped fail deterministically at ~0.18 (r14/r15/r16) for
// reasons not visible at source level. Do not "optimize" this again.
// NOTE r(this): x is now PRE-split in split_kernel with the identical
// split_rtn -> proj MFMA inputs are bit-identical to the verified config.
__device__ __forceinline__ unsigned split_rtn(float v) {
    const unsigned u  = __builtin_bit_cast(unsigned, v);
    const unsigned r  = u + 0x7FFFu + ((u >> 16) & 1u);
    const unsigned hi = r >> 16;
    const float hif   = __builtin_bit_cast(float, r & 0xFFFF0000u);
    const float res   = v - hif;
    const unsigned u2 = __builtin_bit_cast(unsigned, res);
    const unsigned r2 = u2 + 0x7FFFu + ((u2 >> 16) & 1u);
    return (r2 & 0xFFFF0000u) | hi;                    // lo<<16 | hi
}

// ---------------------------------------------------------------------------
// Kernel 1: blk<384  -> split W{k,v,q} into B-fragment-ordered bf16 hi/lo.
//           blk>=384 -> split x into A-fragment-ordered bf16 hi/lo:
//             frag f = mt*32 + ks; lane holds A[row=mt*16+(lane&15)]
//             [k=ks*32+(lane>>4)*8+j], j=0..7 -> xh/xl[f*512 + lane*8 + j].
//             Row index clamped to NROW-1 (matches old proj pad clamp).
// ---------------------------------------------------------------------------
__global__ __launch_bounds__(64) void split_kernel(
    const float* __restrict__ Wk,
    const float* __restrict__ Wv,
    const float* __restrict__ Wq,
    const float* __restrict__ x,
    unsigned short* __restrict__ bwh,
    unsigned short* __restrict__ bwl,
    unsigned short* __restrict__ xh,
    unsigned short* __restrict__ xl)
{
    const int lane = threadIdx.x;
    const int quad = lane >> 4, l4 = lane & 15;

    if (blockIdx.x < 384) {
        const int f    = blockIdx.x;        // 0..383
        const int p    = f >> 7;
        const int rem  = f & 127;
        const int nsub = rem >> 5;
        const int ks   = rem & 31;
        const float* W = (p == 0) ? Wk : (p == 1) ? Wv : Wq;
        const int n = nsub * 16 + l4;

        bf16x8 h, l;
#pragma unroll
        for (int j = 0; j < 8; ++j) {
            const int k = ks * 32 + quad * 8 + j;
            const unsigned hl = split_rtn(W[k * DD + n]);
            h[j] = (short)(hl & 0xFFFFu);
            l[j] = (short)(hl >> 16);
        }
        ((bf16x8*)bwh)[f * 64 + lane] = h;
        ((bf16x8*)bwl)[f * 64 + lane] = l;
    } else {
        const int mt = blockIdx.x - 384;    // 0..255
        int arow = mt * 16 + l4; if (arow > NROW - 1) arow = NROW - 1;
        const float* ap = x + (size_t)arow * CC;
        bf16x8* oh = (bf16x8*)xh + (size_t)(mt * 32) * 64 + lane;
        bf16x8* ol = (bf16x8*)xl + (size_t)(mt * 32) * 64 + lane;

#pragma unroll 4
        for (int ks = 0; ks < 32; ++ks) {
            const int k0 = ks * 32 + quad * 8;
            const f4 xa = *(const f4*)(ap + k0);
            const f4 xb = *(const f4*)(ap + k0 + 4);
            bf16x8 h, l;
#pragma unroll
            for (int j = 0; j < 4; ++j) {
                const unsigned hl = split_rtn(xa[j]);
                h[j] = (short)(hl & 0xFFFFu);
                l[j] = (short)(hl >> 16);
            }
#pragma unroll
            for (int j = 0; j < 4; ++j) {
                const unsigned hl = split_rtn(xb[j]);
                h[4 + j] = (short)(hl & 0xFFFFu);
                l[4 + j] = (short)(hl >> 16);
            }
            oh[ks * 64] = h;
            ol[ks * 64] = l;
        }
    }
}

// ---------------------------------------------------------------------------
// Kernel 2: projections via MFMA 16x16x32 bf16, pre-split fragments.
// 768 single-wave blocks: blk -> (p=blk%3, mt=blk/3). One wave does all
// 4 nsub (full D=64) for its 16-row tile: 16 MFMA/iter, zero split VALU.
// Per-acc product order preserved EXACTLY (ah*bh, ah*bl, al*bh, al*bl)
// -> accumulators bit-identical to the verified r12 config.
// C/D layout (verified): row = (lane>>4)*4 + reg, col = lane&15.
// ---------------------------------------------------------------------------
__global__ __launch_bounds__(64) void proj_mfma_kernel(
    const unsigned short* __restrict__ xh,
    const unsigned short* __restrict__ xl,
    const unsigned short* __restrict__ bwh,
    const unsigned short* __restrict__ bwl,
    float* __restrict__ kT,     // [DD][NROWP] padded
    float* __restrict__ vbuf,   // [NROW][DD]
    float* __restrict__ qbuf)   // [BB*TT][DD]
{
    const int blk  = blockIdx.x;        // 0..767
    const int p    = blk % 3;
    const int mt   = blk / 3;           // 0..255
    const int bs0  = mt * 16;
    const int lane = threadIdx.x;
    const int quad = lane >> 4, l4 = lane & 15;

    const bf16x8* xhp = (const bf16x8*)xh + (size_t)(mt * 32) * 64 + lane;
    const bf16x8* xlp = (const bf16x8*)xl + (size_t)(mt * 32) * 64 + lane;
    const bf16x8* bh  = (const bf16x8*)bwh + (size_t)(p * 4 * 32) * 64 + lane;
    const bf16x8* bl  = (const bf16x8*)bwl + (size_t)(p * 4 * 32) * 64 + lane;

    f32x4 acc[4];
#pragma unroll
    for (int n = 0; n < 4; ++n) acc[n] = (f32x4){0.f, 0.f, 0.f, 0.f};

#pragma unroll 2
    for (int ks = 0; ks < 32; ++ks) {
        const bf16x8 ah = xhp[ks * 64];
        const bf16x8 al = xlp[ks * 64];
#pragma unroll
        for (int n = 0; n < 4; ++n) {
            const bf16x8 bhn = bh[(n * 32 + ks) * 64];
            const bf16x8 bln = bl[(n * 32 + ks) * 64];
            acc[n] = __builtin_amdgcn_mfma_f32_16x16x32_bf16(ah, bhn, acc[n], 0, 0, 0);
            acc[n] = __builtin_amdgcn_mfma_f32_16x16x32_bf16(ah, bln, acc[n], 0, 0, 0);
            acc[n] = __builtin_amdgcn_mfma_f32_16x16x32_bf16(al, bhn, acc[n], 0, 0, 0);
            acc[n] = __builtin_amdgcn_mfma_f32_16x16x32_bf16(al, bln, acc[n], 0, 0, 0);
        }
    }

    // ---- epilogue: D[row=quad*4+reg][col=l4], d = nsub*16 + l4 ----
#pragma unroll
    for (int s = 0; s < 4; ++s) {
        const f32x4 a = acc[s];
        const int d = s * 16 + l4;
#pragma unroll
        for (int reg = 0; reg < 4; ++reg) {
            const int bs = bs0 + quad * 4 + reg;
            if (bs < NROW) {
                const float val = a[reg];
                const int b = bs / SS, ss = bs - b * SS;
                if (p == 0) {
                    kT[(size_t)d * NROWP + b * 1024 + ss] = val;   // padded
                } else if (p == 1) {
                    vbuf[(size_t)bs * DD + d] = val;
                } else {
                    if (ss >= TT - 1)
                        qbuf[((size_t)b * TT + (ss - (TT - 1))) * DD + d] = val;
                }
            }
        }
    }
}

// ---------------------------------------------------------------------------
// Kernel 3: attention, WT=2 windows/block, 1024 blocks x 512 threads.
// Phase 1 now FUSES the q.bias term (ex-qbias kernel): thread (h,p) adds
// sum_{dd in [32h,32h+32)} q[m,dd]*bias[dd,t] into its partial; the cross-h
// part[] sum yields the full logit. Pure fp32 re-association vs the old
// separate qb kernel (error stays bf16-split dominated).
// Softmax: wave wv -> row m=wv>>2, quarter wv&3. Phase 2: sliding v register.
// ---------------------------------------------------------------------------
__global__ __launch_bounds__(512) void attn_kernel(
    const float* __restrict__ kT,     // [DD][NROWP] padded
    const float* __restrict__ vbuf,   // [NROW][DD]
    const float* __restrict__ qbuf,   // [BB*TT][DD]
    const float* __restrict__ bias,   // [DD][TT]
    float* __restrict__ out)          // [BB*TT][DD]
{
    __shared__ __align__(8) float qsT[DD][2];        // [d][m]
    __shared__ __align__(8) float part[2][2][TT];    // [h][m][t]  8 KB
    __shared__ __align__(8) float weiT[TT][2];       // [t][m]     4 KB
    __shared__ float red[16];
    __shared__ float invs[2];
    __shared__ float partial[8][2][DD];              // 4 KB

    const int tid  = threadIdx.x;
    const int lane = tid & 63;
    const int wv   = tid >> 6;          // 0..7
    const int blk  = blockIdx.x;        // 0..1023
    const int b    = blk >> 8;
    const int w0   = (blk & 255) * 2;

    if (tid < 2 * DD) {
        const int m = tid >> 6, dd = tid & 63;
        qsT[dd][m] = qbuf[((size_t)b * TT + w0 + m) * DD + dd];
    }
    __syncthreads();

    // ---- phase 1: q.k (banded) + q.bias, split across h over dd ----
    {
        const int h = tid >> 8, p = tid & 255;
        const int t0 = 2 * p;
        const float* kcol = kT + (size_t)(32 * h) * NROWP + b * 1024 + w0 + t0;
        const float* bp   = bias + (size_t)(32 * h) * TT + t0;
        float a00 = 0.f, a01 = 0.f, a10 = 0.f, a11 = 0.f;   // a[m][j], t=t0+j
#pragma unroll 8
        for (int i = 0; i < 32; ++i) {
            const float* kr = kcol + (size_t)i * NROWP;
            const f2 kA = *(const f2*)kr;         // k[w0+t0], k[w0+t0+1]
            const float kC = kr[2];               // k[w0+t0+2]
            const f2 bv = *(const f2*)(bp + (size_t)i * TT);
            const f2 qv = *(const f2*)&qsT[32 * h + i][0];
            a00 = fmaf(qv[0], kA[0], a00);
            a01 = fmaf(qv[0], kA[1], a01);
            a10 = fmaf(qv[1], kA[1], a10);
            a11 = fmaf(qv[1], kC,    a11);
            a00 = fmaf(qv[0], bv[0], a00);
            a01 = fmaf(qv[0], bv[1], a01);
            a10 = fmaf(qv[1], bv[0], a10);
            a11 = fmaf(qv[1], bv[1], a11);
        }
        *(f2*)&part[h][0][t0] = (f2){a00, a01};
        *(f2*)&part[h][1][t0] = (f2){a10, a11};
    }
    __syncthreads();

    // ---- softmax: wave wv -> row m = wv>>2, quarter qt = wv&3 ----
    {
        const int m = wv >> 2, qt = wv & 3;
        const int tb = qt * 128 + lane;
        float r0 = part[0][m][tb]      + part[1][m][tb];
        float r1 = part[0][m][tb + 64] + part[1][m][tb + 64];
        float mx = fmaxf(r0, r1);
#pragma unroll
        for (int off = 1; off < 64; off <<= 1)
            mx = fmaxf(mx, __shfl_xor(mx, off, 64));
        if (lane == 0) red[wv] = mx;
        __syncthreads();
        mx = fmaxf(fmaxf(red[m * 4], red[m * 4 + 1]),
                   fmaxf(red[m * 4 + 2], red[m * 4 + 3]));
        const float e0 = __expf(r0 - mx), e1 = __expf(r1 - mx);
        weiT[tb][m] = e0;
        weiT[tb + 64][m] = e1;
        float sum = e0 + e1;
#pragma unroll
        for (int off = 1; off < 64; off <<= 1)
            sum += __shfl_xor(sum, off, 64);
        if (lane == 0) red[8 + wv] = sum;
        __syncthreads();
        if (tid < 2)
            invs[tid] = 1.f / (red[8 + tid * 4] + red[9 + tid * 4] +
                               red[10 + tid * 4] + red[11 + tid * 4]);
    }
    __syncthreads();

    // ---- phase 2: PV, wave wv covers 64 t, sliding v register ----
    {
        const int t0r = wv * 64;
        const float* vb = vbuf + ((size_t)b * SS + w0 + t0r) * DD + lane;
        float p0 = 0.f, p1 = 0.f;
        float v0 = vb[0];
#pragma unroll 4
        for (int t = 0; t < 64; ++t) {
            const float v1 = vb[(size_t)(t + 1) * DD];
            const f2 w2 = *(const f2*)&weiT[t0r + t][0];
            p0 = fmaf(w2[0], v0, p0);
            p1 = fmaf(w2[1], v1, p1);
            v0 = v1;
        }
        partial[wv][0][lane] = p0;
        partial[wv][1][lane] = p1;
    }
    __syncthreads();

    // ---- final reduce + store ----
    if (tid < 2 * DD) {
        const int m = tid >> 6, dd = tid & 63;
        float o = 0.f;
#pragma unroll
        for (int j = 0; j < 8; ++j) o += partial[j][m][dd];
        out[((size_t)b * TT + w0 + m) * DD + dd] = o * invs[m];
    }
}

// ---------------------------------------------------------------------------
extern "C" void kernel_launch(void* const* d_in, const int* in_sizes, int n_in,
                              void* d_out, int out_size, void* d_ws, size_t ws_size,
                              hipStream_t stream) {
    const float* x    = (const float*)d_in[0];
    const float* Wk   = (const float*)d_in[1];
    const float* Wv   = (const float*)d_in[2];
    const float* Wq   = (const float*)d_in[3];
    const float* bias = (const float*)d_in[4];
    float* out = (float*)d_out;

    char* ws = (char*)d_ws;
    float* kT             = (float*)(ws + 0);                 // 1 MB
    float* vbuf           = (float*)(ws + (2u  << 20));       // 1.05 MB
    float* qbuf           = (float*)(ws + (4u  << 20));       // 0.52 MB
    unsigned short* bwh   = (unsigned short*)(ws + (6u  << 20));  // 0.39 MB
    unsigned short* bwl   = (unsigned short*)(ws + (8u  << 20));  // 0.39 MB
    unsigned short* xh    = (unsigned short*)(ws + (10u << 20));  // 8 MB
    unsigned short* xl    = (unsigned short*)(ws + (20u << 20));  // 8 MB

    split_kernel<<<640, 64, 0, stream>>>(Wk, Wv, Wq, x, bwh, bwl, xh, xl);
    proj_mfma_kernel<<<768, 64, 0, stream>>>(xh, xl, bwh, bwl, kT, vbuf, qbuf);
    attn_kernel<<<BB * TT / 2, 512, 0, stream>>>(kT, vbuf, qbuf, bias, out);
}

// Round 4
// 115.418 us; speedup vs baseline: 1.0700x; 1.0700x over previous
//
#include <hip/hip_runtime.h>
#include <hip/hip_bf16.h>

#define BB 4      // batch
#define SS 1023   // source length = 2T-1
#define TT 512    // window length
#define CC 1024   // embed dim
#define DD 64     // head size
#define NROW (BB*SS)    // 4092
#define NROWP 4096      // padded kT row stride: kT[d][b*1024 + s]

typedef float f4 __attribute__((ext_vector_type(4)));
typedef float f2 __attribute__((ext_vector_type(2)));
typedef short bf16x8 __attribute__((ext_vector_type(8)));
typedef short s4 __attribute__((ext_vector_type(4)));
typedef float f32x4 __attribute__((ext_vector_type(4)));

// RTN bf16 split: v ~= hi + lo (packed u32 lo<<16|hi).
// SESSION INVARIANT: this split + ALL FOUR MFMA products is the only
// verified-passing config (r12/r13: 0.0156). Manual trunc/half-up splits
// with al*bl dropped fail deterministically at ~0.18 (r14/r15/r16) for
// reasons not visible at source level. Do not "optimize" this again.
__device__ __forceinline__ unsigned split_rtn(float v) {
    const unsigned u  = __builtin_bit_cast(unsigned, v);
    const unsigned r  = u + 0x7FFFu + ((u >> 16) & 1u);
    const unsigned hi = r >> 16;
    const float hif   = __builtin_bit_cast(float, r & 0xFFFF0000u);
    const float res   = v - hif;
    const unsigned u2 = __builtin_bit_cast(unsigned, res);
    const unsigned r2 = u2 + 0x7FFFu + ((u2 >> 16) & 1u);
    return (r2 & 0xFFFF0000u) | hi;                    // lo<<16 | hi
}

// ---------------------------------------------------------------------------
// Kernel 1: split W{k,v,q} into B-fragment-ordered bf16 hi/lo (RTN).
// Frag f = (p*4 + nsub)*32 + ks. Lane holds B[k=ks*32+(lane>>4)*8+j]
// [n=nsub*16+(lane&15)], j=0..7: bw[f*512 + lane*8 + j].  (proven)
// ---------------------------------------------------------------------------
__global__ __launch_bounds__(64) void wsplit_kernel(
    const float* __restrict__ Wk,
    const float* __restrict__ Wv,
    const float* __restrict__ Wq,
    unsigned short* __restrict__ bwh,
    unsigned short* __restrict__ bwl)
{
    const int f    = blockIdx.x;        // 0..383
    const int p    = f >> 7;
    const int rem  = f & 127;
    const int nsub = rem >> 5;
    const int ks   = rem & 31;
    const int lane = threadIdx.x;
    const int quad = lane >> 4, l4 = lane & 15;
    const float* W = (p == 0) ? Wk : (p == 1) ? Wv : Wq;
    const int n = nsub * 16 + l4;

    bf16x8 h, l;
#pragma unroll
    for (int j = 0; j < 8; ++j) {
        const int k = ks * 32 + quad * 8 + j;
        const unsigned hl = split_rtn(W[k * DD + n]);
        h[j] = (short)(hl & 0xFFFFu);
        l[j] = (short)(hl >> 16);
    }
    ((bf16x8*)bwh)[f * 64 + lane] = h;
    ((bf16x8*)bwl)[f * 64 + lane] = l;
}

// ---------------------------------------------------------------------------
// Kernel 2: FUSED x-split + projection MFMA. 768 blocks x 256 threads (4 wv),
// block = (p = blk%3, mt = blk/3). Phase A: stage rows [mt*16, mt*16+16) of x
// into XOR-swizzled LDS hi/lo bf16 planes (coalesced f4 global reads; LDS
// u16 index = row*1024 + (k ^ ((row&7)<<3)) -> write conflict-free, read
// <=2-way (free, m136)). Phase B: wave w owns nsub=w; 32 ks-iters x 4 MFMA,
// per-acc product order EXACTLY (ah*bh, ah*bl, al*bh, al*bl) with the same
// split_rtn values -> accumulators bit-identical to verified r12 config.
// C/D layout (verified): row = (lane>>4)*4 + reg, col = lane&15.
// Occupancy: 64 KB LDS -> 2 blocks/CU = 8 waves/CU (vs 3/CU in r1 proj).
// ---------------------------------------------------------------------------
__global__ __launch_bounds__(256) void proj_fused_kernel(
    const float* __restrict__ x,
    const unsigned short* __restrict__ bwh,
    const unsigned short* __restrict__ bwl,
    float* __restrict__ kT,     // [DD][NROWP] padded
    float* __restrict__ vbuf,   // [NROW][DD]
    float* __restrict__ qbuf)   // [BB*TT][DD]
{
    __shared__ __align__(16) unsigned short lh[16 * 1024];   // 32 KB hi plane
    __shared__ __align__(16) unsigned short ll[16 * 1024];   // 32 KB lo plane

    const int blk  = blockIdx.x;        // 0..767
    const int p    = blk % 3;
    const int mt   = blk / 3;           // 0..255
    const int bs0  = mt * 16;
    const int tid  = threadIdx.x;       // 0..255

    // ---- phase A: stage + split x tile ----
    {
        const int k = tid * 4;          // 0..1020, covers one row per iter
#pragma unroll 4
        for (int i = 0; i < 16; ++i) {
            int arow = bs0 + i; if (arow > NROW - 1) arow = NROW - 1;  // pad clamp
            const f4 xv = *(const f4*)(x + (size_t)arow * CC + k);
            s4 h, l;
#pragma unroll
            for (int j = 0; j < 4; ++j) {
                const unsigned hl = split_rtn(xv[j]);
                h[j] = (short)(hl & 0xFFFFu);
                l[j] = (short)(hl >> 16);
            }
            const int idx = i * 1024 + (k ^ ((i & 7) << 3));
            *(s4*)&lh[idx] = h;
            *(s4*)&ll[idx] = l;
        }
    }
    __syncthreads();

    // ---- phase B: MFMA, wave w = nsub ----
    const int lane = tid & 63;
    const int w    = tid >> 6;          // nsub 0..3
    const int quad = lane >> 4, l4 = lane & 15;

    const bf16x8* bh = (const bf16x8*)bwh
                     + (size_t)((p * 4 + w) * 32) * 64 + lane;
    const bf16x8* bl = (const bf16x8*)bwl
                     + (size_t)((p * 4 + w) * 32) * 64 + lane;

    const int rbase = l4 * 1024;
    const int kxor  = (l4 & 7) << 3;

    f32x4 acc = {0.f, 0.f, 0.f, 0.f};
#pragma unroll 4
    for (int ks = 0; ks < 32; ++ks) {
        const int k0 = ks * 32 + quad * 8;
        const bf16x8 ah = *(const bf16x8*)&lh[rbase + (k0 ^ kxor)];
        const bf16x8 al = *(const bf16x8*)&ll[rbase + (k0 ^ kxor)];
        const bf16x8 bhn = bh[ks * 64];
        const bf16x8 bln = bl[ks * 64];
        acc = __builtin_amdgcn_mfma_f32_16x16x32_bf16(ah, bhn, acc, 0, 0, 0);
        acc = __builtin_amdgcn_mfma_f32_16x16x32_bf16(ah, bln, acc, 0, 0, 0);
        acc = __builtin_amdgcn_mfma_f32_16x16x32_bf16(al, bhn, acc, 0, 0, 0);
        acc = __builtin_amdgcn_mfma_f32_16x16x32_bf16(al, bln, acc, 0, 0, 0);
    }

    // ---- epilogue: D[row=quad*4+reg][col=l4], d = w*16 + l4 ----
    {
        const int d = w * 16 + l4;
#pragma unroll
        for (int reg = 0; reg < 4; ++reg) {
            const int bs = bs0 + quad * 4 + reg;
            if (bs < NROW) {
                const float val = acc[reg];
                const int b = bs / SS, ss = bs - b * SS;
                if (p == 0) {
                    kT[(size_t)d * NROWP + b * 1024 + ss] = val;   // padded
                } else if (p == 1) {
                    vbuf[(size_t)bs * DD + d] = val;
                } else {
                    if (ss >= TT - 1)
                        qbuf[((size_t)b * TT + (ss - (TT - 1))) * DD + d] = val;
                }
            }
        }
    }
}

// ---------------------------------------------------------------------------
// Kernel 3: attention, WT=2 windows/block, 1024 blocks x 512 threads.
// Phase 1 FUSES the q.bias term: thread (h,p) adds
// sum_{dd in [32h,32h+32)} q[m,dd]*bias[dd,t] into its partial; the cross-h
// part[] sum yields the full logit (pure fp32 re-association, verified r1).
// Softmax: wave wv -> row m=wv>>2, quarter wv&3. Phase 2: sliding v register.
// ---------------------------------------------------------------------------
__global__ __launch_bounds__(512) void attn_kernel(
    const float* __restrict__ kT,     // [DD][NROWP] padded
    const float* __restrict__ vbuf,   // [NROW][DD]
    const float* __restrict__ qbuf,   // [BB*TT][DD]
    const float* __restrict__ bias,   // [DD][TT]
    float* __restrict__ out)          // [BB*TT][DD]
{
    __shared__ __align__(8) float qsT[DD][2];        // [d][m]
    __shared__ __align__(8) float part[2][2][TT];    // [h][m][t]  8 KB
    __shared__ __align__(8) float weiT[TT][2];       // [t][m]     4 KB
    __shared__ float red[16];
    __shared__ float invs[2];
    __shared__ float partial[8][2][DD];              // 4 KB

    const int tid  = threadIdx.x;
    const int lane = tid & 63;
    const int wv   = tid >> 6;          // 0..7
    const int blk  = blockIdx.x;        // 0..1023
    const int b    = blk >> 8;
    const int w0   = (blk & 255) * 2;

    if (tid < 2 * DD) {
        const int m = tid >> 6, dd = tid & 63;
        qsT[dd][m] = qbuf[((size_t)b * TT + w0 + m) * DD + dd];
    }
    __syncthreads();

    // ---- phase 1: q.k (banded) + q.bias, split across h over dd ----
    {
        const int h = tid >> 8, p = tid & 255;
        const int t0 = 2 * p;
        const float* kcol = kT + (size_t)(32 * h) * NROWP + b * 1024 + w0 + t0;
        const float* bp   = bias + (size_t)(32 * h) * TT + t0;
        float a00 = 0.f, a01 = 0.f, a10 = 0.f, a11 = 0.f;   // a[m][j], t=t0+j
#pragma unroll 8
        for (int i = 0; i < 32; ++i) {
            const float* kr = kcol + (size_t)i * NROWP;
            const f2 kA = *(const f2*)kr;         // k[w0+t0], k[w0+t0+1]
            const float kC = kr[2];               // k[w0+t0+2]
            const f2 bv = *(const f2*)(bp + (size_t)i * TT);
            const f2 qv = *(const f2*)&qsT[32 * h + i][0];
            a00 = fmaf(qv[0], kA[0], a00);
            a01 = fmaf(qv[0], kA[1], a01);
            a10 = fmaf(qv[1], kA[1], a10);
            a11 = fmaf(qv[1], kC,    a11);
            a00 = fmaf(qv[0], bv[0], a00);
            a01 = fmaf(qv[0], bv[1], a01);
            a10 = fmaf(qv[1], bv[0], a10);
            a11 = fmaf(qv[1], bv[1], a11);
        }
        *(f2*)&part[h][0][t0] = (f2){a00, a01};
        *(f2*)&part[h][1][t0] = (f2){a10, a11};
    }
    __syncthreads();

    // ---- softmax: wave wv -> row m = wv>>2, quarter qt = wv&3 ----
    {
        const int m = wv >> 2, qt = wv & 3;
        const int tb = qt * 128 + lane;
        float r0 = part[0][m][tb]      + part[1][m][tb];
        float r1 = part[0][m][tb + 64] + part[1][m][tb + 64];
        float mx = fmaxf(r0, r1);
#pragma unroll
        for (int off = 1; off < 64; off <<= 1)
            mx = fmaxf(mx, __shfl_xor(mx, off, 64));
        if (lane == 0) red[wv] = mx;
        __syncthreads();
        mx = fmaxf(fmaxf(red[m * 4], red[m * 4 + 1]),
                   fmaxf(red[m * 4 + 2], red[m * 4 + 3]));
        const float e0 = __expf(r0 - mx), e1 = __expf(r1 - mx);
        weiT[tb][m] = e0;
        weiT[tb + 64][m] = e1;
        float sum = e0 + e1;
#pragma unroll
        for (int off = 1; off < 64; off <<= 1)
            sum += __shfl_xor(sum, off, 64);
        if (lane == 0) red[8 + wv] = sum;
        __syncthreads();
        if (tid < 2)
            invs[tid] = 1.f / (red[8 + tid * 4] + red[9 + tid * 4] +
                               red[10 + tid * 4] + red[11 + tid * 4]);
    }
    __syncthreads();

    // ---- phase 2: PV, wave wv covers 64 t, sliding v register ----
    {
        const int t0r = wv * 64;
        const float* vb = vbuf + ((size_t)b * SS + w0 + t0r) * DD + lane;
        float p0 = 0.f, p1 = 0.f;
        float v0 = vb[0];
#pragma unroll 4
        for (int t = 0; t < 64; ++t) {
            const float v1 = vb[(size_t)(t + 1) * DD];
            const f2 w2 = *(const f2*)&weiT[t0r + t][0];
            p0 = fmaf(w2[0], v0, p0);
            p1 = fmaf(w2[1], v1, p1);
            v0 = v1;
        }
        partial[wv][0][lane] = p0;
        partial[wv][1][lane] = p1;
    }
    __syncthreads();

    // ---- final reduce + store ----
    if (tid < 2 * DD) {
        const int m = tid >> 6, dd = tid & 63;
        float o = 0.f;
#pragma unroll
        for (int j = 0; j < 8; ++j) o += partial[j][m][dd];
        out[((size_t)b * TT + w0 + m) * DD + dd] = o * invs[m];
    }
}

// ---------------------------------------------------------------------------
extern "C" void kernel_launch(void* const* d_in, const int* in_sizes, int n_in,
                              void* d_out, int out_size, void* d_ws, size_t ws_size,
                              hipStream_t stream) {
    const float* x    = (const float*)d_in[0];
    const float* Wk   = (const float*)d_in[1];
    const float* Wv   = (const float*)d_in[2];
    const float* Wq   = (const float*)d_in[3];
    const float* bias = (const float*)d_in[4];
    float* out = (float*)d_out;

    char* ws = (char*)d_ws;
    float* kT             = (float*)(ws + 0);                 // 1 MB
    float* vbuf           = (float*)(ws + (2u  << 20));       // 1.05 MB
    float* qbuf           = (float*)(ws + (4u  << 20));       // 0.52 MB
    unsigned short* bwh   = (unsigned short*)(ws + (6u  << 20));  // 0.39 MB
    unsigned short* bwl   = (unsigned short*)(ws + (8u  << 20));  // 0.39 MB

    wsplit_kernel<<<384, 64, 0, stream>>>(Wk, Wv, Wq, bwh, bwl);
    proj_fused_kernel<<<768, 256, 0, stream>>>(x, bwh, bwl, kT, vbuf, qbuf);
    attn_kernel<<<BB * TT / 2, 512, 0, stream>>>(kT, vbuf, qbuf, bias, out);
}

// Round 5
// 109.932 us; speedup vs baseline: 1.1234x; 1.0499x over previous
//
#include <hip/hip_runtime.h>
#include <hip/hip_bf16.h>

#define BB 4      // batch
#define SS 1023   // source length = 2T-1
#define TT 512    // window length
#define CC 1024   // embed dim
#define DD 64     // head size
#define NROW (BB*SS)    // 4092
#define NROWP 4096      // padded kT row stride: kT[d][b*1024 + s]

typedef float f4 __attribute__((ext_vector_type(4)));
typedef float f2 __attribute__((ext_vector_type(2)));
typedef short bf16x8 __attribute__((ext_vector_type(8)));
typedef short s4 __attribute__((ext_vector_type(4)));
typedef float f32x4 __attribute__((ext_vector_type(4)));

// RTN bf16 split: v ~= hi + lo (packed u32 lo<<16|hi).
// SESSION INVARIANT: this split + ALL FOUR MFMA products is the only
// verified-passing config (r12/r13: 0.0156). Manual trunc/half-up splits
// with al*bl dropped fail deterministically at ~0.18 (r14/r15/r16) for
// reasons not visible at source level. Do not "optimize" this again.
__device__ __forceinline__ unsigned split_rtn(float v) {
    const unsigned u  = __builtin_bit_cast(unsigned, v);
    const unsigned r  = u + 0x7FFFu + ((u >> 16) & 1u);
    const unsigned hi = r >> 16;
    const float hif   = __builtin_bit_cast(float, r & 0xFFFF0000u);
    const float res   = v - hif;
    const unsigned u2 = __builtin_bit_cast(unsigned, res);
    const unsigned r2 = u2 + 0x7FFFu + ((u2 >> 16) & 1u);
    return (r2 & 0xFFFF0000u) | hi;                    // lo<<16 | hi
}

// ---------------------------------------------------------------------------
// Kernel 1: split W{k,v,q} into B-fragment-ordered bf16 hi/lo (RTN).
// (verified r4 — unchanged)
// ---------------------------------------------------------------------------
__global__ __launch_bounds__(64) void wsplit_kernel(
    const float* __restrict__ Wk,
    const float* __restrict__ Wv,
    const float* __restrict__ Wq,
    unsigned short* __restrict__ bwh,
    unsigned short* __restrict__ bwl)
{
    const int f    = blockIdx.x;        // 0..383
    const int p    = f >> 7;
    const int rem  = f & 127;
    const int nsub = rem >> 5;
    const int ks   = rem & 31;
    const int lane = threadIdx.x;
    const int quad = lane >> 4, l4 = lane & 15;
    const float* W = (p == 0) ? Wk : (p == 1) ? Wv : Wq;
    const int n = nsub * 16 + l4;

    bf16x8 h, l;
#pragma unroll
    for (int j = 0; j < 8; ++j) {
        const int k = ks * 32 + quad * 8 + j;
        const unsigned hl = split_rtn(W[k * DD + n]);
        h[j] = (short)(hl & 0xFFFFu);
        l[j] = (short)(hl >> 16);
    }
    ((bf16x8*)bwh)[f * 64 + lane] = h;
    ((bf16x8*)bwl)[f * 64 + lane] = l;
}

// ---------------------------------------------------------------------------
// Kernel 2: FUSED x-split + projection MFMA. (verified r4 — unchanged)
// ---------------------------------------------------------------------------
__global__ __launch_bounds__(256) void proj_fused_kernel(
    const float* __restrict__ x,
    const unsigned short* __restrict__ bwh,
    const unsigned short* __restrict__ bwl,
    float* __restrict__ kT,     // [DD][NROWP] padded
    float* __restrict__ vbuf,   // [NROW][DD]
    float* __restrict__ qbuf)   // [BB*TT][DD]
{
    __shared__ __align__(16) unsigned short lh[16 * 1024];   // 32 KB hi plane
    __shared__ __align__(16) unsigned short ll[16 * 1024];   // 32 KB lo plane

    const int blk  = blockIdx.x;        // 0..767
    const int p    = blk % 3;
    const int mt   = blk / 3;           // 0..255
    const int bs0  = mt * 16;
    const int tid  = threadIdx.x;       // 0..255

    // ---- phase A: stage + split x tile ----
    {
        const int k = tid * 4;          // 0..1020, covers one row per iter
#pragma unroll 4
        for (int i = 0; i < 16; ++i) {
            int arow = bs0 + i; if (arow > NROW - 1) arow = NROW - 1;  // pad clamp
            const f4 xv = *(const f4*)(x + (size_t)arow * CC + k);
            s4 h, l;
#pragma unroll
            for (int j = 0; j < 4; ++j) {
                const unsigned hl = split_rtn(xv[j]);
                h[j] = (short)(hl & 0xFFFFu);
                l[j] = (short)(hl >> 16);
            }
            const int idx = i * 1024 + (k ^ ((i & 7) << 3));
            *(s4*)&lh[idx] = h;
            *(s4*)&ll[idx] = l;
        }
    }
    __syncthreads();

    // ---- phase B: MFMA, wave w = nsub ----
    const int lane = tid & 63;
    const int w    = tid >> 6;          // nsub 0..3
    const int quad = lane >> 4, l4 = lane & 15;

    const bf16x8* bh = (const bf16x8*)bwh
                     + (size_t)((p * 4 + w) * 32) * 64 + lane;
    const bf16x8* bl = (const bf16x8*)bwl
                     + (size_t)((p * 4 + w) * 32) * 64 + lane;

    const int rbase = l4 * 1024;
    const int kxor  = (l4 & 7) << 3;

    f32x4 acc = {0.f, 0.f, 0.f, 0.f};
#pragma unroll 4
    for (int ks = 0; ks < 32; ++ks) {
        const int k0 = ks * 32 + quad * 8;
        const bf16x8 ah = *(const bf16x8*)&lh[rbase + (k0 ^ kxor)];
        const bf16x8 al = *(const bf16x8*)&ll[rbase + (k0 ^ kxor)];
        const bf16x8 bhn = bh[ks * 64];
        const bf16x8 bln = bl[ks * 64];
        acc = __builtin_amdgcn_mfma_f32_16x16x32_bf16(ah, bhn, acc, 0, 0, 0);
        acc = __builtin_amdgcn_mfma_f32_16x16x32_bf16(ah, bln, acc, 0, 0, 0);
        acc = __builtin_amdgcn_mfma_f32_16x16x32_bf16(al, bhn, acc, 0, 0, 0);
        acc = __builtin_amdgcn_mfma_f32_16x16x32_bf16(al, bln, acc, 0, 0, 0);
    }

    // ---- epilogue: D[row=quad*4+reg][col=l4], d = w*16 + l4 ----
    {
        const int d = w * 16 + l4;
#pragma unroll
        for (int reg = 0; reg < 4; ++reg) {
            const int bs = bs0 + quad * 4 + reg;
            if (bs < NROW) {
                const float val = acc[reg];
                const int b = bs / SS, ss = bs - b * SS;
                if (p == 0) {
                    kT[(size_t)d * NROWP + b * 1024 + ss] = val;   // padded
                } else if (p == 1) {
                    vbuf[(size_t)bs * DD + d] = val;
                } else {
                    if (ss >= TT - 1)
                        qbuf[((size_t)b * TT + (ss - (TT - 1))) * DD + d] = val;
                }
            }
        }
    }
}

// ---------------------------------------------------------------------------
// Kernel 3: attention, WT=4 windows/block, 512 blocks x 512 threads.
// Phase 1: thread (h=tid>>8, p=tid&255) computes 8 logits (m=0..3, j=0..1,
// t=2p+j) over dd in [32h,32h+32): 5 k-floats (f2+f2+scalar, 8B-aligned,
// shared across the m-band), f2 bias (t-only), broadcast f4 q. q.bias fused
// (verified r1/r4); per-logit fp32 association identical to r4 (k-fma then
// bias-fma per dd, single chain). Traffic/window: 147 KB vs 228 KB at WT=2.
// Softmax: wave wv -> row m=wv>>1, half=wv&1, 4 t/lane. weiT padded [TT][5]
// (write stride 5 -> <=2-way conflicts; phase-2 reads are wave-uniform
// broadcasts). Phase 2: sliding 4-register v window; max v row index
// w0max+3 + 448+63+3... = 508+448+63+3 = 1022 <= SS-1 (in range).
// ---------------------------------------------------------------------------
__global__ __launch_bounds__(512) void attn_kernel(
    const float* __restrict__ kT,     // [DD][NROWP] padded
    const float* __restrict__ vbuf,   // [NROW][DD]
    const float* __restrict__ qbuf,   // [BB*TT][DD]
    const float* __restrict__ bias,   // [DD][TT]
    float* __restrict__ out)          // [BB*TT][DD]
{
    __shared__ __align__(16) float qsT[DD][4];       // [d][m]   1 KB
    __shared__ __align__(8) float part[2][4][TT];    // [h][m][t] 16 KB
    __shared__ float weiT[TT][5];                    // [t][m] padded, 10 KB
    __shared__ float red[16];
    __shared__ float invs[4];
    __shared__ float partial[8][4][DD];              // 8 KB

    const int tid  = threadIdx.x;
    const int lane = tid & 63;
    const int wv   = tid >> 6;          // 0..7
    const int blk  = blockIdx.x;        // 0..511
    const int b    = blk >> 7;
    const int w0   = (blk & 127) * 4;

    if (tid < 4 * DD) {
        const int m = tid >> 6, dd = tid & 63;
        qsT[dd][m] = qbuf[((size_t)b * TT + w0 + m) * DD + dd];
    }
    __syncthreads();

    // ---- phase 1: q.k (banded) + q.bias; 8 logits/thread ----
    {
        const int h = tid >> 8, p = tid & 255;
        const int t0 = 2 * p;
        const float* kcol = kT + (size_t)(32 * h) * NROWP + b * 1024 + w0 + t0;
        const float* bp   = bias + (size_t)(32 * h) * TT + t0;
        // a[m][j]: logit for window w0+m, position t0+j
        float a00 = 0.f, a01 = 0.f, a10 = 0.f, a11 = 0.f;
        float a20 = 0.f, a21 = 0.f, a30 = 0.f, a31 = 0.f;
#pragma unroll 8
        for (int i = 0; i < 32; ++i) {
            const float* kr = kcol + (size_t)i * NROWP;
            const f2 kA = *(const f2*)kr;         // k[base+0], k[base+1]
            const f2 kB = *(const f2*)(kr + 2);   // k[base+2], k[base+3]
            const float kC = kr[4];               // k[base+4]
            const f2 bv = *(const f2*)(bp + (size_t)i * TT);
            const f4 qv = *(const f4*)&qsT[32 * h + i][0];
            // k-term: a[m][j] += q[m] * k[base + m + j]
            a00 = fmaf(qv[0], kA[0], a00);
            a01 = fmaf(qv[0], kA[1], a01);
            a10 = fmaf(qv[1], kA[1], a10);
            a11 = fmaf(qv[1], kB[0], a11);
            a20 = fmaf(qv[2], kB[0], a20);
            a21 = fmaf(qv[2], kB[1], a21);
            a30 = fmaf(qv[3], kB[1], a30);
            a31 = fmaf(qv[3], kC,    a31);
            // bias-term: a[m][j] += q[m] * bias[dd][t0+j]
            a00 = fmaf(qv[0], bv[0], a00);
            a01 = fmaf(qv[0], bv[1], a01);
            a10 = fmaf(qv[1], bv[0], a10);
            a11 = fmaf(qv[1], bv[1], a11);
            a20 = fmaf(qv[2], bv[0], a20);
            a21 = fmaf(qv[2], bv[1], a21);
            a30 = fmaf(qv[3], bv[0], a30);
            a31 = fmaf(qv[3], bv[1], a31);
        }
        *(f2*)&part[h][0][t0] = (f2){a00, a01};
        *(f2*)&part[h][1][t0] = (f2){a10, a11};
        *(f2*)&part[h][2][t0] = (f2){a20, a21};
        *(f2*)&part[h][3][t0] = (f2){a30, a31};
    }
    __syncthreads();

    // ---- softmax: wave wv -> row m = wv>>1, half = wv&1; 4 t per lane ----
    {
        const int m = wv >> 1, half = wv & 1;
        const int tb = half * 256 + lane;
        float r0 = part[0][m][tb]       + part[1][m][tb];
        float r1 = part[0][m][tb + 64]  + part[1][m][tb + 64];
        float r2 = part[0][m][tb + 128] + part[1][m][tb + 128];
        float r3 = part[0][m][tb + 192] + part[1][m][tb + 192];
        float mx = fmaxf(fmaxf(r0, r1), fmaxf(r2, r3));
#pragma unroll
        for (int off = 1; off < 64; off <<= 1)
            mx = fmaxf(mx, __shfl_xor(mx, off, 64));
        if (lane == 0) red[wv] = mx;
        __syncthreads();
        mx = fmaxf(red[m * 2], red[m * 2 + 1]);
        const float e0 = __expf(r0 - mx), e1 = __expf(r1 - mx);
        const float e2 = __expf(r2 - mx), e3 = __expf(r3 - mx);
        weiT[tb][m]       = e0;
        weiT[tb + 64][m]  = e1;
        weiT[tb + 128][m] = e2;
        weiT[tb + 192][m] = e3;
        float sum = (e0 + e1) + (e2 + e3);
#pragma unroll
        for (int off = 1; off < 64; off <<= 1)
            sum += __shfl_xor(sum, off, 64);
        if (lane == 0) red[8 + wv] = sum;
        __syncthreads();
        if (tid < 4)
            invs[tid] = 1.f / (red[8 + tid * 2] + red[9 + tid * 2]);
    }
    __syncthreads();

    // ---- phase 2: PV, wave wv covers 64 t, sliding 4-reg v window ----
    {
        const int t0r = wv * 64;
        const float* vb = vbuf + ((size_t)b * SS + w0 + t0r) * DD + lane;
        float p0 = 0.f, p1 = 0.f, p2 = 0.f, p3 = 0.f;
        float v0 = vb[0];
        float v1 = vb[(size_t)1 * DD];
        float v2 = vb[(size_t)2 * DD];
#pragma unroll 4
        for (int t = 0; t < 64; ++t) {
            const float v3 = vb[(size_t)(t + 3) * DD];
            const float* wt = &weiT[t0r + t][0];   // wave-uniform -> broadcast
            p0 = fmaf(wt[0], v0, p0);
            p1 = fmaf(wt[1], v1, p1);
            p2 = fmaf(wt[2], v2, p2);
            p3 = fmaf(wt[3], v3, p3);
            v0 = v1; v1 = v2; v2 = v3;
        }
        partial[wv][0][lane] = p0;
        partial[wv][1][lane] = p1;
        partial[wv][2][lane] = p2;
        partial[wv][3][lane] = p3;
    }
    __syncthreads();

    // ---- final reduce + store ----
    if (tid < 4 * DD) {
        const int m = tid >> 6, dd = tid & 63;
        float o = 0.f;
#pragma unroll
        for (int j = 0; j < 8; ++j) o += partial[j][m][dd];
        out[((size_t)b * TT + w0 + m) * DD + dd] = o * invs[m];
    }
}

// ---------------------------------------------------------------------------
extern "C" void kernel_launch(void* const* d_in, const int* in_sizes, int n_in,
                              void* d_out, int out_size, void* d_ws, size_t ws_size,
                              hipStream_t stream) {
    const float* x    = (const float*)d_in[0];
    const float* Wk   = (const float*)d_in[1];
    const float* Wv   = (const float*)d_in[2];
    const float* Wq   = (const float*)d_in[3];
    const float* bias = (const float*)d_in[4];
    float* out = (float*)d_out;

    char* ws = (char*)d_ws;
    float* kT             = (float*)(ws + 0);                 // 1 MB
    float* vbuf           = (float*)(ws + (2u  << 20));       // 1.05 MB
    float* qbuf           = (float*)(ws + (4u  << 20));       // 0.52 MB
    unsigned short* bwh   = (unsigned short*)(ws + (6u  << 20));  // 0.39 MB
    unsigned short* bwl   = (unsigned short*)(ws + (8u  << 20));  // 0.39 MB

    wsplit_kernel<<<384, 64, 0, stream>>>(Wk, Wv, Wq, bwh, bwl);
    proj_fused_kernel<<<768, 256, 0, stream>>>(x, bwh, bwl, kT, vbuf, qbuf);
    attn_kernel<<<BB * TT / 4, 512, 0, stream>>>(kT, vbuf, qbuf, bias, out);
}

// Round 6
// 107.445 us; speedup vs baseline: 1.1494x; 1.0232x over previous
//
#include <hip/hip_runtime.h>
#include <hip/hip_bf16.h>

#define BB 4      // batch
#define SS 1023   // source length = 2T-1
#define TT 512    // window length
#define CC 1024   // embed dim
#define DD 64     // head size
#define NROW (BB*SS)    // 4092
#define NROWP 4096      // padded kT row stride: kT[d][b*1024 + s]

typedef float f4 __attribute__((ext_vector_type(4)));
typedef float f2 __attribute__((ext_vector_type(2)));
typedef short bf16x8 __attribute__((ext_vector_type(8)));
typedef short s4 __attribute__((ext_vector_type(4)));
typedef float f32x4 __attribute__((ext_vector_type(4)));

// RTN bf16 split: v ~= hi + lo (packed u32 lo<<16|hi).
// SESSION INVARIANT: this split + ALL FOUR MFMA products is the only
// verified-passing config (r12/r13: 0.0156). Manual trunc/half-up splits
// with al*bl dropped fail deterministically at ~0.18 (r14/r15/r16) for
// reasons not visible at source level. Do not "optimize" this again.
__device__ __forceinline__ unsigned split_rtn(float v) {
    const unsigned u  = __builtin_bit_cast(unsigned, v);
    const unsigned r  = u + 0x7FFFu + ((u >> 16) & 1u);
    const unsigned hi = r >> 16;
    const float hif   = __builtin_bit_cast(float, r & 0xFFFF0000u);
    const float res   = v - hif;
    const unsigned u2 = __builtin_bit_cast(unsigned, res);
    const unsigned r2 = u2 + 0x7FFFu + ((u2 >> 16) & 1u);
    return (r2 & 0xFFFF0000u) | hi;                    // lo<<16 | hi
}

// ---------------------------------------------------------------------------
// Kernel 1: split W{k,v,q} into B-fragment-ordered bf16 hi/lo (RTN).
// (verified r4/r5 — unchanged)
// ---------------------------------------------------------------------------
__global__ __launch_bounds__(64) void wsplit_kernel(
    const float* __restrict__ Wk,
    const float* __restrict__ Wv,
    const float* __restrict__ Wq,
    unsigned short* __restrict__ bwh,
    unsigned short* __restrict__ bwl)
{
    const int f    = blockIdx.x;        // 0..383
    const int p    = f >> 7;
    const int rem  = f & 127;
    const int nsub = rem >> 5;
    const int ks   = rem & 31;
    const int lane = threadIdx.x;
    const int quad = lane >> 4, l4 = lane & 15;
    const float* W = (p == 0) ? Wk : (p == 1) ? Wv : Wq;
    const int n = nsub * 16 + l4;

    bf16x8 h, l;
#pragma unroll
    for (int j = 0; j < 8; ++j) {
        const int k = ks * 32 + quad * 8 + j;
        const unsigned hl = split_rtn(W[k * DD + n]);
        h[j] = (short)(hl & 0xFFFFu);
        l[j] = (short)(hl >> 16);
    }
    ((bf16x8*)bwh)[f * 64 + lane] = h;
    ((bf16x8*)bwl)[f * 64 + lane] = l;
}

// ---------------------------------------------------------------------------
// Kernel 2: FUSED x-split + projection MFMA. (verified r4/r5 — unchanged)
// ---------------------------------------------------------------------------
__global__ __launch_bounds__(256) void proj_fused_kernel(
    const float* __restrict__ x,
    const unsigned short* __restrict__ bwh,
    const unsigned short* __restrict__ bwl,
    float* __restrict__ kT,     // [DD][NROWP] padded
    float* __restrict__ vbuf,   // [NROW][DD]
    float* __restrict__ qbuf)   // [BB*TT][DD]
{
    __shared__ __align__(16) unsigned short lh[16 * 1024];   // 32 KB hi plane
    __shared__ __align__(16) unsigned short ll[16 * 1024];   // 32 KB lo plane

    const int blk  = blockIdx.x;        // 0..767
    const int p    = blk % 3;
    const int mt   = blk / 3;           // 0..255
    const int bs0  = mt * 16;
    const int tid  = threadIdx.x;       // 0..255

    // ---- phase A: stage + split x tile ----
    {
        const int k = tid * 4;          // 0..1020, covers one row per iter
#pragma unroll 4
        for (int i = 0; i < 16; ++i) {
            int arow = bs0 + i; if (arow > NROW - 1) arow = NROW - 1;  // pad clamp
            const f4 xv = *(const f4*)(x + (size_t)arow * CC + k);
            s4 h, l;
#pragma unroll
            for (int j = 0; j < 4; ++j) {
                const unsigned hl = split_rtn(xv[j]);
                h[j] = (short)(hl & 0xFFFFu);
                l[j] = (short)(hl >> 16);
            }
            const int idx = i * 1024 + (k ^ ((i & 7) << 3));
            *(s4*)&lh[idx] = h;
            *(s4*)&ll[idx] = l;
        }
    }
    __syncthreads();

    // ---- phase B: MFMA, wave w = nsub ----
    const int lane = tid & 63;
    const int w    = tid >> 6;          // nsub 0..3
    const int quad = lane >> 4, l4 = lane & 15;

    const bf16x8* bh = (const bf16x8*)bwh
                     + (size_t)((p * 4 + w) * 32) * 64 + lane;
    const bf16x8* bl = (const bf16x8*)bwl
                     + (size_t)((p * 4 + w) * 32) * 64 + lane;

    const int rbase = l4 * 1024;
    const int kxor  = (l4 & 7) << 3;

    f32x4 acc = {0.f, 0.f, 0.f, 0.f};
#pragma unroll 4
    for (int ks = 0; ks < 32; ++ks) {
        const int k0 = ks * 32 + quad * 8;
        const bf16x8 ah = *(const bf16x8*)&lh[rbase + (k0 ^ kxor)];
        const bf16x8 al = *(const bf16x8*)&ll[rbase + (k0 ^ kxor)];
        const bf16x8 bhn = bh[ks * 64];
        const bf16x8 bln = bl[ks * 64];
        acc = __builtin_amdgcn_mfma_f32_16x16x32_bf16(ah, bhn, acc, 0, 0, 0);
        acc = __builtin_amdgcn_mfma_f32_16x16x32_bf16(ah, bln, acc, 0, 0, 0);
        acc = __builtin_amdgcn_mfma_f32_16x16x32_bf16(al, bhn, acc, 0, 0, 0);
        acc = __builtin_amdgcn_mfma_f32_16x16x32_bf16(al, bln, acc, 0, 0, 0);
    }

    // ---- epilogue: D[row=quad*4+reg][col=l4], d = w*16 + l4 ----
    {
        const int d = w * 16 + l4;
#pragma unroll
        for (int reg = 0; reg < 4; ++reg) {
            const int bs = bs0 + quad * 4 + reg;
            if (bs < NROW) {
                const float val = acc[reg];
                const int b = bs / SS, ss = bs - b * SS;
                if (p == 0) {
                    kT[(size_t)d * NROWP + b * 1024 + ss] = val;   // padded
                } else if (p == 1) {
                    vbuf[(size_t)bs * DD + d] = val;
                } else {
                    if (ss >= TT - 1)
                        qbuf[((size_t)b * TT + (ss - (TT - 1))) * DD + d] = val;
                }
            }
        }
    }
}

// ---------------------------------------------------------------------------
// Kernel 3: attention, WT=8 windows/block, 256 blocks x 512 threads.
// Phase 1: thread (h=tid>>8, p=tid&255) computes 16 logits (m=0..7, j=0..1,
// t=2p+j) over dd in [32h,32h+32): 9 k-floats (4xf2+scalar, 8B-aligned,
// shared across the m-band), f2 bias (t-only), 8 broadcast q floats from LDS.
// Per-logit fp32 chain IDENTICAL to verified r5 (k-fma then bias-fma per dd).
// Traffic/window ~49 KB vs 98 KB at WT=4 (kT+vbuf+bias amortized over 8).
// Softmax: wave wv owns window m=wv entirely (8 t/lane, wave-local reduce,
// no cross-wave step). weiT padded [TT][9] (stride-9 writes: 2-way, free).
// Phase 2: sliding 8-register v window; max vbuf row = 504+448+63+7 = 1022
// = SS-1 (in range). LDS ~68 KB -> 1 block/CU at grid=256.
// ---------------------------------------------------------------------------
__global__ __launch_bounds__(512) void attn_kernel(
    const float* __restrict__ kT,     // [DD][NROWP] padded
    const float* __restrict__ vbuf,   // [NROW][DD]
    const float* __restrict__ qbuf,   // [BB*TT][DD]
    const float* __restrict__ bias,   // [DD][TT]
    float* __restrict__ out)          // [BB*TT][DD]
{
    __shared__ __align__(16) float qsT[DD][8];       // [d][m]    2 KB
    __shared__ __align__(8) float part[2][8][TT];    // [h][m][t] 32 KB
    __shared__ float weiT[TT][9];                    // [t][m] padded, 18 KB
    __shared__ float invs[8];
    __shared__ float partial[8][8][DD];              // 16 KB

    const int tid  = threadIdx.x;
    const int lane = tid & 63;
    const int wv   = tid >> 6;          // 0..7
    const int blk  = blockIdx.x;        // 0..255
    const int b    = blk >> 6;
    const int w0   = (blk & 63) * 8;

    if (tid < 8 * DD) {                 // all 512 threads
        const int m = tid >> 6, dd = tid & 63;
        qsT[dd][m] = qbuf[((size_t)b * TT + w0 + m) * DD + dd];
    }
    __syncthreads();

    // ---- phase 1: q.k (banded) + q.bias; 16 logits/thread ----
    {
        const int h = tid >> 8, p = tid & 255;
        const int t0 = 2 * p;
        const float* kcol = kT + (size_t)(32 * h) * NROWP + b * 1024 + w0 + t0;
        const float* bp   = bias + (size_t)(32 * h) * TT + t0;
        float am[8][2];
#pragma unroll
        for (int m = 0; m < 8; ++m) { am[m][0] = 0.f; am[m][1] = 0.f; }
#pragma unroll 4
        for (int i = 0; i < 32; ++i) {
            const float* kr = kcol + (size_t)i * NROWP;
            const f2 k01 = *(const f2*)kr;
            const f2 k23 = *(const f2*)(kr + 2);
            const f2 k45 = *(const f2*)(kr + 4);
            const f2 k67 = *(const f2*)(kr + 6);
            const float k8 = kr[8];
            const f2 bv = *(const f2*)(bp + (size_t)i * TT);
            const f4 qA = *(const f4*)&qsT[32 * h + i][0];
            const f4 qB = *(const f4*)&qsT[32 * h + i][4];
            const float kk[9] = {k01[0], k01[1], k23[0], k23[1],
                                 k45[0], k45[1], k67[0], k67[1], k8};
            const float qq[8] = {qA[0], qA[1], qA[2], qA[3],
                                 qB[0], qB[1], qB[2], qB[3]};
#pragma unroll
            for (int m = 0; m < 8; ++m) {
                // per-logit chain: k-fma then bias-fma (verified r5 order)
                am[m][0] = fmaf(qq[m], kk[m],     am[m][0]);
                am[m][0] = fmaf(qq[m], bv[0],     am[m][0]);
                am[m][1] = fmaf(qq[m], kk[m + 1], am[m][1]);
                am[m][1] = fmaf(qq[m], bv[1],     am[m][1]);
            }
        }
#pragma unroll
        for (int m = 0; m < 8; ++m)
            *(f2*)&part[h][m][t0] = (f2){am[m][0], am[m][1]};
    }
    __syncthreads();

    // ---- softmax: wave wv owns window m = wv; 8 t per lane ----
    {
        const int m = wv;
        float r[8];
#pragma unroll
        for (int j = 0; j < 8; ++j) {
            const int t = lane + 64 * j;
            r[j] = part[0][m][t] + part[1][m][t];
        }
        float mx = r[0];
#pragma unroll
        for (int j = 1; j < 8; ++j) mx = fmaxf(mx, r[j]);
#pragma unroll
        for (int off = 1; off < 64; off <<= 1)
            mx = fmaxf(mx, __shfl_xor(mx, off, 64));
        float sum = 0.f;
#pragma unroll
        for (int j = 0; j < 8; ++j) {
            const float e = __expf(r[j] - mx);
            weiT[lane + 64 * j][m] = e;
            sum += e;
        }
#pragma unroll
        for (int off = 1; off < 64; off <<= 1)
            sum += __shfl_xor(sum, off, 64);
        if (lane == 0) invs[m] = 1.f / sum;
    }
    __syncthreads();

    // ---- phase 2: PV, wave wv covers 64 t, sliding 8-reg v window ----
    {
        const int t0r = wv * 64;
        const float* vb = vbuf + ((size_t)b * SS + w0 + t0r) * DD + lane;
        float pm[8];
#pragma unroll
        for (int m = 0; m < 8; ++m) pm[m] = 0.f;
        float vv[8];
#pragma unroll
        for (int m = 0; m < 7; ++m) vv[m] = vb[(size_t)m * DD];
#pragma unroll 2
        for (int t = 0; t < 64; ++t) {
            vv[7] = vb[(size_t)(t + 7) * DD];
            const float* wt = &weiT[t0r + t][0];   // wave-uniform -> broadcast
#pragma unroll
            for (int m = 0; m < 8; ++m)
                pm[m] = fmaf(wt[m], vv[m], pm[m]);
#pragma unroll
            for (int m = 0; m < 7; ++m) vv[m] = vv[m + 1];
        }
#pragma unroll
        for (int m = 0; m < 8; ++m)
            partial[wv][m][lane] = pm[m];
    }
    __syncthreads();

    // ---- final reduce + store ----
    {
        const int m = tid >> 6, dd = tid & 63;
        float o = 0.f;
#pragma unroll
        for (int j = 0; j < 8; ++j) o += partial[j][m][dd];
        out[((size_t)b * TT + w0 + m) * DD + dd] = o * invs[m];
    }
}

// ---------------------------------------------------------------------------
extern "C" void kernel_launch(void* const* d_in, const int* in_sizes, int n_in,
                              void* d_out, int out_size, void* d_ws, size_t ws_size,
                              hipStream_t stream) {
    const float* x    = (const float*)d_in[0];
    const float* Wk   = (const float*)d_in[1];
    const float* Wv   = (const float*)d_in[2];
    const float* Wq   = (const float*)d_in[3];
    const float* bias = (const float*)d_in[4];
    float* out = (float*)d_out;

    char* ws = (char*)d_ws;
    float* kT             = (float*)(ws + 0);                 // 1 MB
    float* vbuf           = (float*)(ws + (2u  << 20));       // 1.05 MB
    float* qbuf           = (float*)(ws + (4u  << 20));       // 0.52 MB
    unsigned short* bwh   = (unsigned short*)(ws + (6u  << 20));  // 0.39 MB
    unsigned short* bwl   = (unsigned short*)(ws + (8u  << 20));  // 0.39 MB

    wsplit_kernel<<<384, 64, 0, stream>>>(Wk, Wv, Wq, bwh, bwl);
    proj_fused_kernel<<<768, 256, 0, stream>>>(x, bwh, bwl, kT, vbuf, qbuf);
    attn_kernel<<<BB * TT / 8, 512, 0, stream>>>(kT, vbuf, qbuf, bias, out);
}